// Round 1
// baseline (97.316 us; speedup 1.0000x reference)
//
#include <hip/hip_runtime.h>

namespace {
constexpr int HIN = 130, WIN = 130;
constexpr int HH = 128, WW = 128;
constexpr int C = 128, CR = 32, G = 8, CG = 16, KK = 9, B = 8;

// Transpose W_reduce (32x128) -> WredT (128x32) so the main kernel's
// fully-unrolled r-loop reads 32 contiguous uniform floats (s_load_dwordx16).
__global__ void transpose_wred(const float* __restrict__ Wred, float* __restrict__ WredT) {
    int idx = blockIdx.x * 256 + threadIdx.x;   // 4096 elements total
    int r = idx >> 7;
    int c = idx & 127;
    WredT[c * CR + r] = Wred[r * C + c];
}

__global__ __launch_bounds__(256) void invol_main(
    const float* __restrict__ x,      // [B][C][130][130]
    const float* __restrict__ WredT,  // [128][32]
    const float* __restrict__ bred,   // [32]
    const float* __restrict__ Wkern,  // [72][32]
    const float* __restrict__ bkern,  // [72]
    float* __restrict__ out)          // [B][C][128][128]
{
    const int pix = blockIdx.x * 256 + threadIdx.x;
    const int b = pix >> 14;            // H*W = 16384
    const int h = (pix >> 7) & (HH - 1);
    const int w = pix & (WW - 1);

    const float* xb  = x + (size_t)b * C * HIN * WIN;
    const float* xcp = xb + (size_t)(h + 1) * WIN + (w + 1);   // center tap

    // Stage 1: red[r] = bred[r] + sum_c WredT[c][r] * x[b,c,h+1,w+1]
    float red[CR];
#pragma unroll
    for (int r = 0; r < CR; ++r) red[r] = bred[r];

#pragma unroll 16
    for (int c = 0; c < C; ++c) {
        float xv = xcp[c * (HIN * WIN)];
#pragma unroll
        for (int r = 0; r < CR; ++r)
            red[r] = fmaf(WredT[c * CR + r], xv, red[r]);
    }

    const float* xrow = xb + (size_t)h * WIN + w;              // tap (0,0)
    float* op = out + ((size_t)(b * C) * HH + h) * WW + w;

    // Stage 2+3 per group: 9 kernel values, then apply to 16 channels
    for (int g = 0; g < G; ++g) {
        float kern[KK];
#pragma unroll
        for (int k = 0; k < KK; ++k) {
            const int o = g * KK + k;
            float acc = bkern[o];
#pragma unroll
            for (int r = 0; r < CR; ++r)
                acc = fmaf(Wkern[o * CR + r], red[r], acc);
            kern[k] = acc;
        }
#pragma unroll 4
        for (int cc = 0; cc < CG; ++cc) {
            const int c = g * CG + cc;
            const float* xp = xrow + (size_t)c * (HIN * WIN);
            float acc = 0.f;
#pragma unroll
            for (int i = 0; i < 3; ++i)
#pragma unroll
                for (int j = 0; j < 3; ++j)
                    acc = fmaf(kern[i * 3 + j], xp[i * WIN + j], acc);
            op[(size_t)c * HH * WW] = acc;
        }
    }
}
} // namespace

extern "C" void kernel_launch(void* const* d_in, const int* in_sizes, int n_in,
                              void* d_out, int out_size, void* d_ws, size_t ws_size,
                              hipStream_t stream) {
    const float* x     = (const float*)d_in[0];
    const float* Wred  = (const float*)d_in[1];
    const float* bred  = (const float*)d_in[2];
    const float* Wkern = (const float*)d_in[3];
    const float* bkern = (const float*)d_in[4];
    float* out   = (float*)d_out;
    float* WredT = (float*)d_ws;   // 128*32*4 = 16 KB scratch

    transpose_wred<<<16, 256, 0, stream>>>(Wred, WredT);

    const int npix = B * HH * WW;          // 131072
    invol_main<<<npix / 256, 256, 0, stream>>>(x, WredT, bred, Wkern, bkern, out);
}

// Round 2
// 97.259 us; speedup vs baseline: 1.0006x; 1.0006x over previous
//
#include <hip/hip_runtime.h>

namespace {
constexpr int HIN = 130, WIN = 130;
constexpr int HH = 128, WW = 128;
constexpr int C = 128, CR = 32, G = 8, CG = 16, B = 8;

// Transpose W_reduce (32x128) -> WredT (128x32): the r-loop then reads
// contiguous uniform floats (scalarized to s_load_dwordx*).
__global__ void transpose_wred(const float* __restrict__ Wred, float* __restrict__ WredT) {
    int idx = blockIdx.x * 256 + threadIdx.x;   // 4096 elements
    int r = idx >> 7;
    int c = idx & 127;
    WredT[c * CR + r] = Wred[r * C + c];
}

// Block = 256 threads = 64 pixels x 4 roles.
//   role q = tid>>6 (wave-uniform), pixel p = tid&63.
//   stage1: q computes red[8q..8q+8) for its pixel -> LDS (one barrier)
//   stage2: q computes kern for groups {2q, 2q+1} (18 vals, registers only)
//   stage3: q applies those groups to channels [32q, 32q+32), coalesced.
__global__ __launch_bounds__(256) void invol_fused(
    const float* __restrict__ x,      // [B][C][130][130]
    const float* __restrict__ WredT,  // [128][32]
    const float* __restrict__ bred,   // [32]
    const float* __restrict__ Wkern,  // [72][32]
    const float* __restrict__ bkern,  // [72]
    float* __restrict__ out)          // [B][C][128][128]
{
    __shared__ float red_lds[64][CR + 1];   // 64x33 floats = 8448 B, 2-way banks (free)

    const int t = threadIdx.x;
    const int p = t & 63;
    const int q = __builtin_amdgcn_readfirstlane(t >> 6);   // force SGPR

    const int blk = blockIdx.x;                // 2048 blocks
    const int w0  = (blk & 1) << 6;            // 0 or 64
    const int h   = (blk >> 1) & (HH - 1);
    const int b   = blk >> 8;

    const float* xb  = x + (size_t)b * C * HIN * WIN;
    const int wpix = w0 + p;

    // ---- stage 1: red[8q..8q+8) ----
    const float* xc = xb + (size_t)(h + 1) * WIN + (wpix + 1);   // center tap
    float racc[8];
#pragma unroll
    for (int r = 0; r < 8; ++r) racc[r] = bred[q * 8 + r];

#pragma unroll 8
    for (int c = 0; c < C; ++c) {
        float xv = xc[(size_t)c * (HIN * WIN)];
#pragma unroll
        for (int r = 0; r < 8; ++r)
            racc[r] = fmaf(WredT[c * CR + q * 8 + r], xv, racc[r]);
    }
#pragma unroll
    for (int r = 0; r < 8; ++r) red_lds[p][q * 8 + r] = racc[r];
    __syncthreads();

    // ---- stage 2: kern for o = 18q .. 18q+17 (groups 2q, 2q+1) ----
    float kern[18];
#pragma unroll
    for (int k = 0; k < 18; ++k) kern[k] = bkern[18 * q + k];

#pragma unroll
    for (int r = 0; r < CR; ++r) {
        float rv = red_lds[p][r];
#pragma unroll
        for (int k = 0; k < 18; ++k)
            kern[k] = fmaf(Wkern[(18 * q + k) * CR + r], rv, kern[k]);
    }

    // ---- stage 3: apply to channels [32q, 32q+32) ----
    const float* xrow = xb + (size_t)h * WIN + wpix;   // tap (0,0)
    float* op = out + (((size_t)(b * C + 32 * q)) * HH + h) * WW + wpix;

#pragma unroll
    for (int half = 0; half < 2; ++half) {             // group 2q+half
#pragma unroll 4
        for (int cc = 0; cc < CG; ++cc) {
            const int crel = 16 * half + cc;
            const float* xp = xrow + (size_t)(32 * q + crel) * (HIN * WIN);
            float acc = 0.f;
#pragma unroll
            for (int i = 0; i < 3; ++i)
#pragma unroll
                for (int j = 0; j < 3; ++j)
                    acc = fmaf(kern[9 * half + i * 3 + j], xp[i * WIN + j], acc);
            op[(size_t)crel * HH * WW] = acc;
        }
    }
}
} // namespace

extern "C" void kernel_launch(void* const* d_in, const int* in_sizes, int n_in,
                              void* d_out, int out_size, void* d_ws, size_t ws_size,
                              hipStream_t stream) {
    const float* x     = (const float*)d_in[0];
    const float* Wred  = (const float*)d_in[1];
    const float* bred  = (const float*)d_in[2];
    const float* Wkern = (const float*)d_in[3];
    const float* bkern = (const float*)d_in[4];
    float* out   = (float*)d_out;
    float* WredT = (float*)d_ws;   // 16 KB scratch

    transpose_wred<<<16, 256, 0, stream>>>(Wred, WredT);

    // 8 b * 128 h * 2 wseg = 2048 blocks
    invol_fused<<<2048, 256, 0, stream>>>(x, WredT, bred, Wkern, bkern, out);
}

// Round 4
// 93.618 us; speedup vs baseline: 1.0395x; 1.0389x over previous
//
#include <hip/hip_runtime.h>

namespace {
constexpr int HIN = 130, WIN = 130;
constexpr int HH = 128, WW = 128;
constexpr int C = 128, CR = 32, B = 8;
constexpr int CHW = HIN * WIN;   // 16900

// Transpose W_reduce (32x128) -> WredT (128x32): r-loop reads contiguous
// uniform floats (scalarized to s_load_dwordx*).
__global__ void transpose_wred(const float* __restrict__ Wred, float* __restrict__ WredT) {
    int idx = blockIdx.x * 256 + threadIdx.x;   // 4096 elements
    int r = idx >> 7;
    int c = idx & 127;
    WredT[c * CR + r] = Wred[r * C + c];
}

// Block = 256 threads = 64 pixels (lanes) x 4 waves (roles).
// Role q = wave id: owns channels [32q,32q+32), groups {2q,2q+1}.
//   stage1: red[8q..8q+8) per pixel -> red_lds (barrier)
//   stage2: kern[18] for its 2 groups, registers only
//   stage3: 8 chunks of 4 channels; taps staged to wave-private LDS rows,
//           double-buffered. One __syncthreads per chunk orders the
//           cross-lane LDS dependence (compiler can't see it per-lane).
__global__ __launch_bounds__(256, 4) void invol_fused(
    const float* __restrict__ x,      // [B][C][130][130]
    const float* __restrict__ WredT,  // [128][32]
    const float* __restrict__ bred,   // [32]
    const float* __restrict__ Wkern,  // [72][32]
    const float* __restrict__ bkern,  // [72]
    float* __restrict__ out)          // [B][C][128][128]
{
    __shared__ float red_lds[64][CR + 1];   // 8448 B
    __shared__ float xs[2][48][66];         // 25344 B  (rows 12q..12q+11 owned by wave q)

    const int t = threadIdx.x;
    const int p = t & 63;
    const int q = __builtin_amdgcn_readfirstlane(t >> 6);   // wave-uniform role

    const int blk = blockIdx.x;                // 2048 blocks
    const int w0  = (blk & 1) << 6;            // 0 or 64
    const int h   = (blk >> 1) & (HH - 1);
    const int b   = blk >> 8;

    const float* xb = x + (size_t)b * C * CHW;

    // ---- prologue: issue chunk-0 tap stage loads (channels 32q..32q+3) ----
    float sv[12], se[12];
    {
        const float* base = xb + (size_t)(32 * q) * CHW + (size_t)h * WIN + w0;
#pragma unroll
        for (int rep = 0; rep < 12; ++rep) {
            const float* rp = base + (rep / 3) * CHW + (rep % 3) * WIN;
            sv[rep] = rp[p];
            if (p < 2) se[rep] = rp[64 + p];
        }
    }

    // ---- stage 1: red[8q..8q+8) ----
    const float* xc = xb + (size_t)(h + 1) * WIN + (w0 + p + 1);
    float racc[8];
#pragma unroll
    for (int r = 0; r < 8; ++r) racc[r] = bred[q * 8 + r];

#pragma unroll
    for (int cb = 0; cb < 4; ++cb) {
        float xv[32];
#pragma unroll
        for (int cc = 0; cc < 32; ++cc)
            xv[cc] = xc[(size_t)(cb * 32 + cc) * CHW];
#pragma unroll
        for (int cc = 0; cc < 32; ++cc) {
#pragma unroll
            for (int r = 0; r < 8; ++r)
                racc[r] = fmaf(WredT[(cb * 32 + cc) * CR + q * 8 + r], xv[cc], racc[r]);
        }
    }
#pragma unroll
    for (int r = 0; r < 8; ++r) red_lds[p][q * 8 + r] = racc[r];

    // write chunk-0 stage into xs[0] (wave-private rows)
#pragma unroll
    for (int rep = 0; rep < 12; ++rep) {
        xs[0][12 * q + rep][p] = sv[rep];
        if (p < 2) xs[0][12 * q + rep][64 + p] = se[rep];
    }
    __syncthreads();

    // ---- stage 2: kern for o = 18q .. 18q+17 (groups 2q, 2q+1), registers ----
    float kern[18];
#pragma unroll
    for (int k = 0; k < 18; ++k) kern[k] = bkern[18 * q + k];
#pragma unroll
    for (int r = 0; r < CR; ++r) {
        float rv = red_lds[p][r];
#pragma unroll
        for (int k = 0; k < 18; ++k)
            kern[k] = fmaf(Wkern[(18 * q + k) * CR + r], rv, kern[k]);
    }

    // ---- stage 3: 8 chunks x 4 channels, double-buffered ----
    float* op = out + (((size_t)(b * C + 32 * q)) * HH + h) * WW + w0 + p;

#pragma unroll
    for (int ch = 0; ch < 8; ++ch) {
        const int buf = ch & 1;
        // T14: issue next-chunk global loads early (hide under consume)
        if (ch < 7) {
            const float* base = xb + (size_t)(32 * q + 4 * (ch + 1)) * CHW
                                   + (size_t)h * WIN + w0;
#pragma unroll
            for (int rep = 0; rep < 12; ++rep) {
                const float* rp = base + (rep / 3) * CHW + (rep % 3) * WIN;
                sv[rep] = rp[p];
                if (p < 2) se[rep] = rp[64 + p];
            }
        }
        // consume chunk ch: group-half = ch>>2 (static), channels 4ch..4ch+3
#pragma unroll
        for (int m = 0; m < 4; ++m) {
            float acc = 0.f;
#pragma unroll
            for (int i = 0; i < 3; ++i)
#pragma unroll
                for (int j = 0; j < 3; ++j)
                    acc = fmaf(kern[9 * (ch >> 2) + 3 * i + j],
                               xs[buf][12 * q + 3 * m + i][p + j], acc);
            op[(size_t)(4 * ch + m) * HH * WW] = acc;
        }
        // write next-chunk stage into the other buffer, then order the
        // cross-lane LDS dependence for the next iteration.
        if (ch < 7) {
#pragma unroll
            for (int rep = 0; rep < 12; ++rep) {
                xs[buf ^ 1][12 * q + rep][p] = sv[rep];
                if (p < 2) xs[buf ^ 1][12 * q + rep][64 + p] = se[rep];
            }
            __syncthreads();
        }
    }
}
} // namespace

extern "C" void kernel_launch(void* const* d_in, const int* in_sizes, int n_in,
                              void* d_out, int out_size, void* d_ws, size_t ws_size,
                              hipStream_t stream) {
    const float* x     = (const float*)d_in[0];
    const float* Wred  = (const float*)d_in[1];
    const float* bred  = (const float*)d_in[2];
    const float* Wkern = (const float*)d_in[3];
    const float* bkern = (const float*)d_in[4];
    float* out   = (float*)d_out;
    float* WredT = (float*)d_ws;   // 16 KB scratch

    transpose_wred<<<16, 256, 0, stream>>>(Wred, WredT);

    // 8 b * 128 h * 2 wseg = 2048 blocks
    invol_fused<<<2048, 256, 0, stream>>>(x, WredT, bred, Wkern, bkern, out);
}

// Round 5
// 72.469 us; speedup vs baseline: 1.3429x; 1.2918x over previous
//
#include <hip/hip_runtime.h>

namespace {
constexpr int HIN = 130, WIN = 130;
constexpr int HH = 128, WW = 128;
constexpr int C = 128, CR = 32, B = 8;
constexpr int CHW = HIN * WIN;   // 16900

// Transpose W_reduce (32x128) -> WredT (128x32): r-loop reads contiguous
// uniform floats (scalarized to s_load_dwordx*).
__global__ void transpose_wred(const float* __restrict__ Wred, float* __restrict__ WredT) {
    int idx = blockIdx.x * 256 + threadIdx.x;   // 4096 elements
    int r = idx >> 7;
    int c = idx & 127;
    WredT[c * CR + r] = Wred[r * C + c];
}

// In-wave LDS ordering fence (rule-18 pattern): the cross-lane write->read
// dependence in wave-private LDS is invisible to per-lane alias analysis;
// lgkmcnt(0) + sched_barrier(0) orders it without a workgroup barrier.
__device__ __forceinline__ void lds_fence() {
    asm volatile("s_waitcnt lgkmcnt(0)" ::: "memory");
    __builtin_amdgcn_sched_barrier(0);
}

// Block = 256 threads = 64 pixels (lanes) x 4 waves.
// Wave q owns channels [32q,32q+32) and groups {2q,2q+1}; stage-3 LDS is
// wave-private -> zero barriers in the chunk loop (fences only). Single
// s_barrier (lgkmcnt-only, no vmcnt drain) covers the red_lds cross-wave edge.
__global__ __launch_bounds__(256, 4) void invol_fused(
    const float* __restrict__ x,      // [B][C][130][130]
    const float* __restrict__ WredT,  // [128][32]
    const float* __restrict__ bred,   // [32]
    const float* __restrict__ Wkern,  // [72][32]
    const float* __restrict__ bkern,  // [72]
    float* __restrict__ out)          // [B][C][128][128]
{
    __shared__ float red_lds[64][CR + 1];   // 8448 B
    __shared__ float xs[4][12][66];         // 12672 B, wave-private rows

    const int t = threadIdx.x;
    const int p = t & 63;
    const int q = __builtin_amdgcn_readfirstlane(t >> 6);

    // XCD-chunked swizzle: 2048 blocks, 8 XCDs -> XCD k owns batch k, so
    // h-adjacent blocks (sharing 2/3 of their row footprint) share an L2.
    const int orig = blockIdx.x;
    const int blk  = (orig & 7) * 256 + (orig >> 3);   // bijective (2048 % 8 == 0)
    const int b    = blk >> 8;
    const int h    = (blk >> 1) & (HH - 1);
    const int w0   = (blk & 1) << 6;

    const float* xb = x + (size_t)b * C * CHW;

    // ---- stage 1: red[8q..8q+8) ----
    const float* xc = xb + (size_t)(h + 1) * WIN + (w0 + p + 1);
    float racc[8];
#pragma unroll
    for (int r = 0; r < 8; ++r) racc[r] = bred[q * 8 + r];

#pragma unroll
    for (int cb = 0; cb < 4; ++cb) {
        float xv[32];
#pragma unroll
        for (int cc = 0; cc < 32; ++cc)
            xv[cc] = xc[(size_t)(cb * 32 + cc) * CHW];
#pragma unroll
        for (int cc = 0; cc < 32; ++cc) {
#pragma unroll
            for (int r = 0; r < 8; ++r)
                racc[r] = fmaf(WredT[(cb * 32 + cc) * CR + q * 8 + r], xv[cc], racc[r]);
        }
    }
#pragma unroll
    for (int r = 0; r < 8; ++r) red_lds[p][q * 8 + r] = racc[r];

    // ---- prefetch chunk 0 (channels 32q..32q+3): 12 rows of 66 as float2 ----
    float2 nv[12];
    if (p < 33) {
        const float* base = xb + (size_t)(32 * q) * CHW + (size_t)h * WIN + w0 + 2 * p;
#pragma unroll
        for (int rep = 0; rep < 12; ++rep)
            nv[rep] = *(const float2*)(base + (rep / 3) * CHW + (rep % 3) * WIN);
    }

    // Cross-wave barrier for red_lds: lgkmcnt only — the 12 prefetch loads
    // stay in flight and hide under stage 2's FMAs (no vmcnt drain).
    asm volatile("s_waitcnt lgkmcnt(0)\n\ts_barrier" ::: "memory");
    __builtin_amdgcn_sched_barrier(0);

    // ---- stage 2: kern[18] for groups {2q,2q+1}, registers only ----
    float kern[18];
#pragma unroll
    for (int k = 0; k < 18; ++k) kern[k] = bkern[18 * q + k];
#pragma unroll
    for (int r = 0; r < CR; ++r) {
        float rv = red_lds[p][r];
#pragma unroll
        for (int k = 0; k < 18; ++k)
            kern[k] = fmaf(Wkern[(18 * q + k) * CR + r], rv, kern[k]);
    }

    // write chunk 0 (vmcnt wait on nv inserted by compiler)
    if (p < 33) {
#pragma unroll
        for (int rep = 0; rep < 12; ++rep)
            *(float2*)&xs[q][rep][2 * p] = nv[rep];
    }
    lds_fence();

    // ---- stage 3: 8 chunks x 4 channels, wave-private, barrier-free ----
    float* op = out + (((size_t)(b * C + 32 * q)) * HH + h) * WW + w0 + p;

#pragma unroll
    for (int ch = 0; ch < 8; ++ch) {
        // issue next-chunk loads early (hide under this chunk's consume)
        if (ch < 7 && p < 33) {
            const float* base = xb + (size_t)(32 * q + 4 * (ch + 1)) * CHW
                                   + (size_t)h * WIN + w0 + 2 * p;
#pragma unroll
            for (int rep = 0; rep < 12; ++rep)
                nv[rep] = *(const float2*)(base + (rep / 3) * CHW + (rep % 3) * WIN);
        }
        // consume chunk ch (reads xs rows written last iteration)
#pragma unroll
        for (int m = 0; m < 4; ++m) {
            float acc = 0.f;
#pragma unroll
            for (int i = 0; i < 3; ++i)
#pragma unroll
                for (int j = 0; j < 3; ++j)
                    acc = fmaf(kern[9 * (ch >> 2) + 3 * i + j],
                               xs[q][3 * m + i][p + j], acc);
            op[(size_t)(4 * ch + m) * HH * WW] = acc;
        }
        // overwrite wave-private rows with next chunk, fence for next iter
        if (ch < 7) {
            if (p < 33) {
#pragma unroll
                for (int rep = 0; rep < 12; ++rep)
                    *(float2*)&xs[q][rep][2 * p] = nv[rep];
            }
            lds_fence();
        }
    }
}
} // namespace

extern "C" void kernel_launch(void* const* d_in, const int* in_sizes, int n_in,
                              void* d_out, int out_size, void* d_ws, size_t ws_size,
                              hipStream_t stream) {
    const float* x     = (const float*)d_in[0];
    const float* Wred  = (const float*)d_in[1];
    const float* bred  = (const float*)d_in[2];
    const float* Wkern = (const float*)d_in[3];
    const float* bkern = (const float*)d_in[4];
    float* out   = (float*)d_out;
    float* WredT = (float*)d_ws;   // 16 KB scratch

    transpose_wred<<<16, 256, 0, stream>>>(Wred, WredT);

    // 8 b * 128 h * 2 wseg = 2048 blocks
    invol_fused<<<2048, 256, 0, stream>>>(x, WredT, bred, Wkern, bkern, out);
}